// Round 3
// baseline (137.555 us; speedup 1.0000x reference)
//
#include <hip/hip_runtime.h>
#include <hip/hip_bf16.h>

#define INNER 31999
#define VOCAB 32000
#define DEPTH 18
#define M_DIM 64      // B*T = 4*16
#define K_DIM 512     // D

typedef __attribute__((ext_vector_type(8))) short bf16x8;
typedef __attribute__((ext_vector_type(4))) float f32x4;

__device__ __forceinline__ short f2bf(float f) {
    union { float f; unsigned int u; } c; c.f = f;
    unsigned int u = c.u;
    u += 0x7fffu + ((u >> 16) & 1u);   // round-to-nearest-even
    return (short)(u >> 16);
}

__device__ __forceinline__ bf16x8 cvt8(float4 lo, float4 hi) {
    bf16x8 r;
    r[0] = f2bf(lo.x); r[1] = f2bf(lo.y); r[2] = f2bf(lo.z); r[3] = f2bf(lo.w);
    r[4] = f2bf(hi.x); r[5] = f2bf(hi.y); r[6] = f2bf(hi.z); r[7] = f2bf(hi.w);
    return r;
}

// Kernel 0: convert att (64x512 fp32) to bf16 once. 32 blocks x 256 thr x 4 elems.
__global__ __launch_bounds__(256) void conv_att_kernel(
    const float* __restrict__ att, unsigned short* __restrict__ attb)
{
    const int i = (blockIdx.x * 256 + threadIdx.x) * 4;
    const float4 v = *(const float4*)(att + i);
    ushort4 o;
    o.x = (unsigned short)f2bf(v.x);
    o.y = (unsigned short)f2bf(v.y);
    o.z = (unsigned short)f2bf(v.z);
    o.w = (unsigned short)f2bf(v.w);
    *(ushort4*)(attb + i) = o;
}

// Kernel 1: xT[n][m] = sum_k W[n][k]*att[m][k], fp32 MFMA accum, fp16 store.
// Block = 128 thr (2 waves), wave handles 16 W-rows x all 64 m.
// Grid 1000 -> 2000 waves (2/SIMD). W read (65.5 MB) is the HBM floor.
__global__ __launch_bounds__(128) void gemm_xt_kernel(
    const float* __restrict__ W,              // [31999][512] fp32
    const unsigned short* __restrict__ attb,  // [64][512] bf16
    _Float16* __restrict__ xT)                // [32000][64] fp16
{
    const int wave = threadIdx.x >> 6;
    const int lane = threadIdx.x & 63;
    const int mrow = lane & 15;
    const int quad = lane >> 4;
    const int n_base = blockIdx.x * 32 + wave * 16;

    // Clamp the single OOB row (n==31999); its xT row is never gathered.
    const int n = n_base + mrow;
    const int nc = n < INNER ? n : (INNER - 1);
    const float* wp = W + (size_t)nc * K_DIM;

    f32x4 acc[4];
    #pragma unroll
    for (int j = 0; j < 4; j++) acc[j] = (f32x4){0.f, 0.f, 0.f, 0.f};

    #pragma unroll 4
    for (int k0 = 0; k0 < K_DIM; k0 += 32) {
        const int koff = k0 + quad * 8;            // this lane's 8 k values
        const float4* p = (const float4*)(wp + koff);
        const bf16x8 a = cvt8(p[0], p[1]);         // W rows: A operand
        #pragma unroll
        for (int j = 0; j < 4; j++) {
            const bf16x8 b = *(const bf16x8*)(attb + (j * 16 + mrow) * K_DIM + koff);
            acc[j] = __builtin_amdgcn_mfma_f32_16x16x32_bf16(a, b, acc[j], 0, 0, 0);
        }
    }

    // D layout: col(lane&15) = m-within-16, row(quad*4+reg) = W-row offset.
    #pragma unroll
    for (int j = 0; j < 4; j++) {
        const int m = j * 16 + mrow;
        #pragma unroll
        for (int r = 0; r < 4; r++)
            xT[(size_t)(n_base + quad * 4 + r) * M_DIM + m] = (_Float16)acc[j][r];
    }
}

// Kernel 2: out[m][v] = sum_d clamp(logsigmoid(s*x), log eps, 0)
//   = sum_d min(y_d,0) - log( prod_d (1 + exp(-|y_d|)) )   [one log per output]
// prod in (1, 2^18]: <=18 ulp rel err. Per-d clip never fires (|x| <~ 6).
// xT in fp16: 4.1 MB working set -> L2-resident per XCD; 128 B coalesced row
// gathers. Sign fold via bit ops on the fp32-converted value.
__global__ __launch_bounds__(256) void hsoftmax_kernel(
    const _Float16* __restrict__ xT,       // [32000][64] fp16
    const int*   __restrict__ path_index,  // [VOCAB*DEPTH]
    const float* __restrict__ path_sign,   // [VOCAB*DEPTH]
    float* __restrict__ out)               // [64][32000]
{
    __shared__ unsigned int packed[32 * DEPTH];   // idx | signbit (idx < 2^15)
    __shared__ float res[32][M_DIM + 1];          // [v][m], +1 pad

    const int tid = threadIdx.x;
    const int wave = tid >> 6;
    const int lane = tid & 63;                    // lane = m
    const int v_base = blockIdx.x * 32;
    const int base = v_base * DEPTH;

    for (int t = tid; t < 32 * DEPTH; t += 256) {
        const unsigned int idx = (unsigned int)path_index[base + t];
        const float s = path_sign[base + t];
        packed[t] = idx | (s < 0.f ? 0x80000000u : 0u);
    }
    __syncthreads();

    for (int i = 0; i < 8; i++) {
        const int vloc = wave * 8 + i;
        float accmin = 0.f;
        float prod = 1.f;
        #pragma unroll
        for (int d = 0; d < DEPTH; d++) {
            const unsigned int p = packed[vloc * DEPTH + d];       // broadcast
            const float x = (float)xT[(p & 0x7fffu) * M_DIM + lane]; // 128B coalesced
            const unsigned int xb = __float_as_uint(x);
            const float negabs = __uint_as_float(xb | 0x80000000u);  // -|y|
            const float y = __uint_as_float(xb ^ (p & 0x80000000u)); // s*x
            prod *= 1.f + __expf(negabs);
            accmin += fminf(y, 0.f);
        }
        const float r = accmin - __logf(prod);
        res[vloc][lane] = fmaxf(r, -373.1f);      // 18*log(1e-9) safety net
    }
    __syncthreads();

    // Coalesced stores: 256 thr x 8 iters cover 64 m x 32 v.
    #pragma unroll
    for (int it = 0; it < 8; it++) {
        const int m = it * 8 + (tid >> 5);
        const int vloc = tid & 31;
        out[(size_t)m * VOCAB + v_base + vloc] = res[vloc][m];
    }
}

extern "C" void kernel_launch(void* const* d_in, const int* in_sizes, int n_in,
                              void* d_out, int out_size, void* d_ws, size_t ws_size,
                              hipStream_t stream) {
    const float* att        = (const float*)d_in[0];
    const float* W          = (const float*)d_in[1];
    const int*   path_index = (const int*)d_in[2];
    const float* path_sign  = (const float*)d_in[3];
    // d_in[4] = path_bias: algebraically redundant ((1-sign)/2), unused.

    _Float16* xT = (_Float16*)d_ws;                          // 32000*64*2 = 4.096 MB
    unsigned short* attb = (unsigned short*)((char*)d_ws + (size_t)VOCAB * M_DIM * 2); // 64 KB
    float* out = (float*)d_out;

    conv_att_kernel<<<32, 256, 0, stream>>>(att, attb);
    gemm_xt_kernel<<<1000, 128, 0, stream>>>(W, attb, xT);
    hsoftmax_kernel<<<1000, 256, 0, stream>>>(xT, path_index, path_sign, out);
}